// Round 5
// baseline (192.675 us; speedup 1.0000x reference)
//
#include <hip/hip_runtime.h>

// GAE backward scan. B=4096 rows, T=2048, fp32. Latency/phase-bound at R3's
// 64us (2x roofline): phased kernels load->vmcnt(0)->scan with all resident
// waves in lockstep, so the memory pipe idles during every scan phase.
//
// R5: wave-per-row, 4 backward segments of 512 (lane owns 8 contiguous ->
// same proven-ideal coalescing), STRAIGHT-LINE depth-2 software pipeline:
//   load(s3); load(s2); scan3; load(s1); scan2; load(s0); scan1; scan0
// No loops, no register rotation, no launch_bounds VGPR cap (R4's suspected
// spill/replay hazard), no barriers, no LDS. Scan math identical to the
// R2/R3-validated shuffle suffix scan.

constexpr float GAMMA  = 0.99f;
constexpr float LMBDA  = 0.95f;
constexpr int   T      = 2048;
constexpr int   SEGLEN = 512;
constexpr int   EPT    = SEGLEN / 64;   // 8 elements per lane per segment
constexpr int   WPB    = 4;             // waves (rows) per 256-thread block

struct Raw {
    float4 r0, r1; int4 t0, t1; float4 v0, v1; float4 n0, n1;
};

__device__ __forceinline__ Raw load_raw(const float* __restrict__ reward,
                                        const int*   __restrict__ term,
                                        const float* __restrict__ value,
                                        const float* __restrict__ next_value,
                                        size_t o)
{
    Raw x;
    x.r0 = ((const float4*)(reward     + o))[0];
    x.r1 = ((const float4*)(reward     + o))[1];
    x.t0 = ((const int4*  )(term       + o))[0];
    x.t1 = ((const int4*  )(term       + o))[1];
    x.v0 = ((const float4*)(value      + o))[0];
    x.v1 = ((const float4*)(value      + o))[1];
    x.n0 = ((const float4*)(next_value + o))[0];
    x.n1 = ((const float4*)(next_value + o))[1];
    return x;
}

// Scan one 512-element segment (wave-wide), store adv/ret, return the carry
// leaving the segment's left edge: g_out = A_seg + B_seg * g_in.
__device__ __forceinline__ float seg_scan_store(const Raw& x, int lane, float g,
                                                float* __restrict__ adv_out,
                                                float* __restrict__ ret_out,
                                                size_t o)
{
    float r [EPT] = {x.r0.x, x.r0.y, x.r0.z, x.r0.w, x.r1.x, x.r1.y, x.r1.z, x.r1.w};
    float nd[EPT] = {1.f - (float)x.t0.x, 1.f - (float)x.t0.y, 1.f - (float)x.t0.z, 1.f - (float)x.t0.w,
                     1.f - (float)x.t1.x, 1.f - (float)x.t1.y, 1.f - (float)x.t1.z, 1.f - (float)x.t1.w};
    float vv[EPT] = {x.v0.x, x.v0.y, x.v0.z, x.v0.w, x.v1.x, x.v1.y, x.v1.z, x.v1.w};
    float nv[EPT] = {x.n0.x, x.n0.y, x.n0.z, x.n0.w, x.n1.x, x.n1.y, x.n1.z, x.n1.w};

    // Intra-lane backward scan with zero carry.
    float loc[EPT], P[EPT];
    float gg = 0.f, p = 1.f;
    #pragma unroll
    for (int t = EPT - 1; t >= 0; --t) {
        float c     = (GAMMA * LMBDA) * nd[t];
        float delta = fmaf(GAMMA * nv[t], nd[t], r[t]) - vv[t];
        gg = fmaf(c, gg, delta);
        p *= c;
        loc[t] = gg;
        P[t]   = p;
    }

    // Wave-wide inclusive suffix-composition scan of (A, Bc).
    float A = loc[0], Bc = P[0];
    #pragma unroll
    for (int off = 1; off < 64; off <<= 1) {
        float a2 = __shfl_down(A,  off, 64);
        float b2 = __shfl_down(Bc, off, 64);
        if (lane + off < 64) {
            A  = fmaf(Bc, a2, A);
            Bc *= b2;
        }
    }

    // Exclusive suffix (carry entering this lane's chunk before segment carry).
    float eA = __shfl_down(A,  1, 64);
    float eB = __shfl_down(Bc, 1, 64);
    if (lane == 63) { eA = 0.f; eB = 1.f; }

    // Segment exit carry: lane 0's inclusive affine applied to g, broadcast.
    const float gout = __shfl(fmaf(Bc, g, A), 0, 64);

    const float gin = fmaf(eB, g, eA);

    float a0 = fmaf(P[0], gin, loc[0]), a1 = fmaf(P[1], gin, loc[1]);
    float a2 = fmaf(P[2], gin, loc[2]), a3 = fmaf(P[3], gin, loc[3]);
    float a4 = fmaf(P[4], gin, loc[4]), a5 = fmaf(P[5], gin, loc[5]);
    float a6 = fmaf(P[6], gin, loc[6]), a7 = fmaf(P[7], gin, loc[7]);

    ((float4*)(adv_out + o))[0] = make_float4(a0, a1, a2, a3);
    ((float4*)(adv_out + o))[1] = make_float4(a4, a5, a6, a7);
    ((float4*)(ret_out + o))[0] = make_float4(a0 + vv[0], a1 + vv[1], a2 + vv[2], a3 + vv[3]);
    ((float4*)(ret_out + o))[1] = make_float4(a4 + vv[4], a5 + vv[5], a6 + vv[6], a7 + vv[7]);

    return gout;
}

__global__ __launch_bounds__(256) void gae_kernel(
    const float* __restrict__ reward,
    const int*   __restrict__ term,
    const float* __restrict__ value,
    const float* __restrict__ next_value,
    float* __restrict__ adv_out,
    float* __restrict__ ret_out,
    int B)
{
    const int wave = threadIdx.x >> 6;
    const int lane = threadIdx.x & 63;
    const int row  = blockIdx.x * WPB + wave;
    if (row >= B) return;

    const size_t rowbase = (size_t)row * T + (size_t)lane * EPT;
    const size_t o3 = rowbase + 3 * SEGLEN;
    const size_t o2 = rowbase + 2 * SEGLEN;
    const size_t o1 = rowbase + 1 * SEGLEN;
    const size_t o0 = rowbase;

    // Depth-2 straight-line pipeline: next segment's loads are in flight
    // while the current segment is scanned/stored.
    Raw x3 = load_raw(reward, term, value, next_value, o3);
    Raw x2 = load_raw(reward, term, value, next_value, o2);
    float g = 0.f;
    g = seg_scan_store(x3, lane, g, adv_out, ret_out, o3);
    Raw x1 = load_raw(reward, term, value, next_value, o1);
    g = seg_scan_store(x2, lane, g, adv_out, ret_out, o2);
    Raw x0 = load_raw(reward, term, value, next_value, o0);
    g = seg_scan_store(x1, lane, g, adv_out, ret_out, o1);
    (void)seg_scan_store(x0, lane, g, adv_out, ret_out, o0);
}

extern "C" void kernel_launch(void* const* d_in, const int* in_sizes, int n_in,
                              void* d_out, int out_size, void* d_ws, size_t ws_size,
                              hipStream_t stream) {
    const float* reward     = (const float*)d_in[0];
    const int*   term       = (const int*  )d_in[1];
    const float* value      = (const float*)d_in[2];
    const float* next_value = (const float*)d_in[3];

    const int BT = in_sizes[0];
    const int B  = BT / T;

    float* adv = (float*)d_out;
    float* ret = adv + BT;

    const int grid = (B + WPB - 1) / WPB;
    gae_kernel<<<grid, 64 * WPB, 0, stream>>>(
        reward, term, value, next_value, adv, ret, B);
}

// Round 6
// 190.409 us; speedup vs baseline: 1.0119x; 1.0119x over previous
//
#include <hip/hip_runtime.h>

// GAE backward scan. B=4096 rows, T=2048, fp32. Latency-bound at ~64us
// (2x roofline): Little's law from R5 counters shows <1 outstanding load
// per wave on average -- the compiler's pressure-driven scheduler sinks
// prefetch loads to their uses (R5 VGPR=36 proves it), serializing
// load->wait->scan phases.
//
// R6: whole row per wave, ALL 32 dwordx4 loads issued up front (nothing
// downstream frees pressure by sinking -- fold consumes them immediately),
// fold to c/delta/v (96 regs, raw dies), shuffle suffix scan, epilogue
// RECOMPUTES the recurrence with the true carry (no loc/P arrays: -64
// VGPRs vs R2, which spilled). __launch_bounds__(256,2) -> 256-VGPR cap:
// no spills, no incentive to sink. 4096 waves x 32KB in flight.

constexpr float GAMMA = 0.99f;
constexpr float LMBDA = 0.95f;
constexpr float GL    = GAMMA * LMBDA;
constexpr int   T     = 2048;
constexpr int   EPL   = 32;   // elements per lane (whole row per wave)
constexpr int   WPB   = 4;    // independent rows per 256-thread block

__global__ __launch_bounds__(256, 2) void gae_kernel(
    const float* __restrict__ reward,
    const int*   __restrict__ term,
    const float* __restrict__ value,
    const float* __restrict__ next_value,
    float* __restrict__ adv_out,
    float* __restrict__ ret_out,
    int B)
{
    const int wave = threadIdx.x >> 6;
    const int lane = threadIdx.x & 63;
    const int row  = blockIdx.x * WPB + wave;
    if (row >= B) return;

    const size_t base = (size_t)row * T + (size_t)lane * EPL;
    const float4* rp = (const float4*)(reward     + base);
    const int4*   tp = (const int4*  )(term       + base);
    const float4* vp = (const float4*)(value      + base);
    const float4* np = (const float4*)(next_value + base);

    // ---- phase 1: issue ALL loads (32 dwordx4 in flight per lane) ----
    float4 r4[8]; int4 t4[8]; float4 v4[8]; float4 n4[8];
    #pragma unroll
    for (int q = 0; q < 8; ++q) r4[q] = rp[q];
    #pragma unroll
    for (int q = 0; q < 8; ++q) n4[q] = np[q];
    #pragma unroll
    for (int q = 0; q < 8; ++q) t4[q] = tp[q];
    #pragma unroll
    for (int q = 0; q < 8; ++q) v4[q] = vp[q];

    // ---- phase 2: fold raw -> (c, delta); v4 stays live for ret ----
    float c[EPL], d[EPL];
    #pragma unroll
    for (int q = 0; q < 8; ++q) {
        const float nd0 = 1.f - (float)t4[q].x;
        const float nd1 = 1.f - (float)t4[q].y;
        const float nd2 = 1.f - (float)t4[q].z;
        const float nd3 = 1.f - (float)t4[q].w;
        c[4*q+0] = GL * nd0;  c[4*q+1] = GL * nd1;
        c[4*q+2] = GL * nd2;  c[4*q+3] = GL * nd3;
        d[4*q+0] = fmaf(GAMMA * n4[q].x, nd0, r4[q].x) - v4[q].x;
        d[4*q+1] = fmaf(GAMMA * n4[q].y, nd1, r4[q].y) - v4[q].y;
        d[4*q+2] = fmaf(GAMMA * n4[q].z, nd2, r4[q].z) - v4[q].z;
        d[4*q+3] = fmaf(GAMMA * n4[q].w, nd3, r4[q].w) - v4[q].w;
    }

    // ---- phase 3: intra-lane affine (A, Bc): carry_out = A + Bc*carry_in
    float A = 0.f, Bc = 1.f;
    #pragma unroll
    for (int t = EPL - 1; t >= 0; --t) {
        A  = fmaf(c[t], A, d[t]);
        Bc *= c[t];
    }

    // ---- phase 4: wave-wide inclusive suffix-composition scan ----
    #pragma unroll
    for (int off = 1; off < 64; off <<= 1) {
        float a2 = __shfl_down(A,  off, 64);
        float b2 = __shfl_down(Bc, off, 64);
        if (lane + off < 64) {
            A  = fmaf(Bc, a2, A);
            Bc *= b2;
        }
    }
    // Carry entering this lane's chunk (row's global carry is 0).
    float gin = __shfl_down(A, 1, 64);
    if (lane == 63) gin = 0.f;

    // ---- phase 5: recompute recurrence with true carry, store ----
    float4* advp = (float4*)(adv_out + base);
    float4* retp = (float4*)(ret_out + base);
    float g = gin;
    #pragma unroll
    for (int q = 7; q >= 0; --q) {
        float a0, a1, a2, a3;
        g = fmaf(c[4*q+3], g, d[4*q+3]); a3 = g;
        g = fmaf(c[4*q+2], g, d[4*q+2]); a2 = g;
        g = fmaf(c[4*q+1], g, d[4*q+1]); a1 = g;
        g = fmaf(c[4*q+0], g, d[4*q+0]); a0 = g;
        advp[q] = make_float4(a0, a1, a2, a3);
        retp[q] = make_float4(a0 + v4[q].x, a1 + v4[q].y,
                              a2 + v4[q].z, a3 + v4[q].w);
    }
}

extern "C" void kernel_launch(void* const* d_in, const int* in_sizes, int n_in,
                              void* d_out, int out_size, void* d_ws, size_t ws_size,
                              hipStream_t stream) {
    const float* reward     = (const float*)d_in[0];
    const int*   term       = (const int*  )d_in[1];
    const float* value      = (const float*)d_in[2];
    const float* next_value = (const float*)d_in[3];

    const int BT = in_sizes[0];
    const int B  = BT / T;

    float* adv = (float*)d_out;
    float* ret = adv + BT;

    const int grid = (B + WPB - 1) / WPB;
    gae_kernel<<<grid, 64 * WPB, 0, stream>>>(
        reward, term, value, next_value, adv, ret, B);
}